// Round 6
// baseline (353.335 us; speedup 1.0000x reference)
//
#include <hip/hip_runtime.h>
#include <hip/hip_cooperative_groups.h>
#include <stdint.h>

namespace cg = cooperative_groups;

#define N_NODES 6144
#define GSIZE 24
#define NGRAPH 256
#define DIN 128
#define DH 64
#define EFF 512
#define EPSN 1e-5f

typedef __attribute__((ext_vector_type(8))) __bf16 bf16x8;
typedef __attribute__((ext_vector_type(4))) float f32x4;
union U16B { uint4 u; bf16x8 v; unsigned short s[8]; };

__device__ inline float bf2f(unsigned short u){ return __uint_as_float(((unsigned)u)<<16); }
__device__ inline unsigned short f2bf(float f){
  unsigned u = __float_as_uint(f);
  u += 0x7fff + ((u>>16)&1);
  return (unsigned short)(u>>16);
}
__device__ inline float gelu_exact(float x){ return 0.5f*x*(1.0f+erff(x*0.70710678118654752f)); }

// ---- workspace float offsets ----
#define XP    0        // 256 graphs x 256 floats (x col sum/sumsq partials)
#define HP    65536    // 256 graphs x 128 floats (h col sum/sumsq partials)
#define WT1   98304
#define WT2   102400
#define PWT1  106496
#define FBo   110592   // 257 floats
#define WCVT_BYTE 450560   // 3 x 512 x 128 bf16 = 393216 B
#define QKV_BYTE  851968   // 3 x 6144 x 512 bf16 = 18.9 MB

// arena byte offsets (block-shared scratch, phases separated by syncs)
// hv [0,6528) persists C->D. Phase A: red 8192/red2 10240.
// Phase B: redA 8192, cst 10240, A1 11264, C1 11776, stage 12288..47104.
// Phase C: qs 8192, ks 21248, vs 34304, S 47360..52736.
// Phase D: redA 8192, stat 10240, A2 10752, C2 11008, a3 11264, c3 11520,
//          scores 11776, wsm 11872, hs 12288, hn 18528, ts 24768..31008.

__global__ __launch_bounds__(512, 1)
void k_mega(const float* __restrict__ x,
            const float* __restrict__ wq, const float* __restrict__ bq,
            const float* __restrict__ wk, const float* __restrict__ bk,
            const float* __restrict__ wv, const float* __restrict__ bv,
            const float* __restrict__ nq_w, const float* __restrict__ nq_b,
            const float* __restrict__ nq_ms,
            const float* __restrict__ no_w, const float* __restrict__ no_b,
            const float* __restrict__ no_ms,
            const float* __restrict__ o_w1, const float* __restrict__ o_b1,
            const float* __restrict__ o_w2, const float* __restrict__ o_b2,
            const float* __restrict__ pn_w, const float* __restrict__ pn_b,
            const float* __restrict__ pn_ms,
            const float* __restrict__ p_w1, const float* __restrict__ p_b1,
            const float* __restrict__ p_w2, const float* __restrict__ p_b2,
            float* __restrict__ ws, float* __restrict__ out)
{
  cg::grid_group grid = cg::this_grid();
  __shared__ __align__(16) char arena[53248];
  int t = threadIdx.x;
  int g = blockIdx.x;
  int base = g * GSIZE;
  unsigned short* qkv  = (unsigned short*)((char*)ws + QKV_BYTE);
  unsigned short* wcvt = (unsigned short*)((char*)ws + WCVT_BYTE);
  float (*hv)[68] = (float(*)[68])(arena);

  // ================= Phase A: x col-stat partials + weight prep =================
  {
    float* red  = (float*)(arena + 8192);
    float* red2 = (float*)(arena + 10240);
    int c = t & 127, r0 = t >> 7;
    const float* xp = x + (size_t)(base + r0)*DIN + c;
    float s = 0.f, q = 0.f;
    #pragma unroll
    for(int r = 0; r < 6; ++r){ float v = xp[(size_t)r*4*DIN]; s += v; q += v*v; }
    red[t] = s; red2[t] = q;
    if(g < 3){
      const float* src = (g==0) ? o_w1 : (g==1) ? o_w2 : p_w1;
      float* dst = ws + ((g==0) ? WT1 : (g==1) ? WT2 : PWT1);
      for(int p = t; p < DH*DH; p += 512){ int r = p>>6, cc = p&63; dst[cc*DH + r] = src[p]; }
    } else if(g == 3){
      float* fb = ws + FBo;
      if(t < 64){ fb[t] = o_b1[t]; fb[64+t] = o_b2[t]; fb[128+t] = p_b1[t]; fb[192+t] = p_w2[t]; }
      if(t == 0) fb[256] = p_b2[0];
    } else if(g < 16){
      int j = g - 4; int mat = j >> 2, seg = j & 3;
      const float* src = (mat==0) ? wq : (mat==1) ? wk : wv;
      unsigned short* dst = wcvt + (size_t)mat*EFF*DIN + seg*16384;
      const float* sp = src + seg*16384;
      for(int e = t*8; e < 16384; e += 4096){
        float4 a = *(const float4*)(sp + e);
        float4 b = *(const float4*)(sp + e + 4);
        U16B o;
        o.s[0]=f2bf(a.x); o.s[1]=f2bf(a.y); o.s[2]=f2bf(a.z); o.s[3]=f2bf(a.w);
        o.s[4]=f2bf(b.x); o.s[5]=f2bf(b.y); o.s[6]=f2bf(b.z); o.s[7]=f2bf(b.w);
        *(uint4*)(dst + e) = o.u;
      }
    }
    __syncthreads();
    if(t < 128){
      ws[XP + g*256 + t]       = red[t]  + red[t+128]  + red[t+256]  + red[t+384];
      ws[XP + g*256 + 128 + t] = red2[t] + red2[t+128] + red2[t+256] + red2[t+384];
    }
  }
  grid.sync();

  // ================= Phase B: reduce stats + QKV MFMA =================
  {
    float* redA = (float*)(arena + 8192);
    float* cst  = (float*)(arena + 10240);
    float* A1   = (float*)(arena + 11264);
    float* C1   = (float*)(arena + 11776);
    {
      int idx = t & 255, half = t >> 8;
      float s = 0.f;
      for(int p = half; p < NGRAPH; p += 2) s += ws[XP + p*256 + idx];
      redA[t] = s;
    }
    __syncthreads();
    if(t < 256) cst[t] = redA[t] + redA[t+256];
    __syncthreads();
    if(t < 128){
      float mean = cst[t] * (1.0f / N_NODES);
      float ex2  = cst[128+t] * (1.0f / N_NODES);
      float cm   = mean * nq_ms[t];
      float var  = ex2 - 2.f*cm*mean + cm*cm;
      float rstd = rsqrtf(var + EPSN);
      float a    = nq_w[t] * rstd;
      A1[t] = a; C1[t] = nq_b[t] - a*cm;
    }
    __syncthreads();
    unsigned short* stage = (unsigned short*)(arena + 12288);
    int wave = t >> 6, lane = t & 63, m = lane & 15, quad = lane >> 4;
    unsigned short* st = stage + wave*2176;          // [16][136] shorts
    int gw = g*8 + wave;
    for(int task = gw; task < 4608; task += 2048){
      int rt = task % 384;
      int rem = task / 384;
      int y = rem % 3, z = rem / 3;
      int row = rt*16 + m;
      const float* bias = (y==0) ? bq : (y==1) ? bk : bv;
      const unsigned short* wp = wcvt + (size_t)y*EFF*DIN;
      bf16x8 xfr[4];
      #pragma unroll
      for(int kk = 0; kk < 4; kk++){
        int k0 = kk*32 + quad*8;
        float4 a = *(const float4*)(x + (size_t)row*DIN + k0);
        float4 b = *(const float4*)(x + (size_t)row*DIN + k0 + 4);
        U16B u;
        u.s[0] = f2bf(a.x*A1[k0+0] + C1[k0+0]);
        u.s[1] = f2bf(a.y*A1[k0+1] + C1[k0+1]);
        u.s[2] = f2bf(a.z*A1[k0+2] + C1[k0+2]);
        u.s[3] = f2bf(a.w*A1[k0+3] + C1[k0+3]);
        u.s[4] = f2bf(b.x*A1[k0+4] + C1[k0+4]);
        u.s[5] = f2bf(b.y*A1[k0+5] + C1[k0+5]);
        u.s[6] = f2bf(b.z*A1[k0+6] + C1[k0+6]);
        u.s[7] = f2bf(b.w*A1[k0+7] + C1[k0+7]);
        xfr[kk] = u.v;
      }
      for(int i = 0; i < 8; i++){
        int ct = z*8 + i;
        int wrow = ct*16 + m;
        f32x4 acc = {0.f,0.f,0.f,0.f};
        #pragma unroll
        for(int kk = 0; kk < 4; kk++){
          int k0 = kk*32 + quad*8;
          U16B b8; b8.u = *(const uint4*)(wp + (size_t)wrow*DIN + k0);
          acc = __builtin_amdgcn_mfma_f32_16x16x32_bf16(b8.v, xfr[kk], acc, 0, 0, 0);
        }
        int ch0 = ct*16 + quad*4;
        float4 bv4 = *(const float4*)(bias + ch0);
        int chr = i*16 + quad*4;
        union { uint2 u; unsigned short s[4]; } o;
        o.s[0] = f2bf(acc[0] + bv4.x);
        o.s[1] = f2bf(acc[1] + bv4.y);
        o.s[2] = f2bf(acc[2] + bv4.z);
        o.s[3] = f2bf(acc[3] + bv4.w);
        *(uint2*)(st + m*136 + chr) = o.u;
      }
      #pragma unroll
      for(int j = 0; j < 4; j++){
        int cgi = lane + j*64;
        int nl = cgi >> 4, ck = cgi & 15;
        uint4 v = *(const uint4*)(st + nl*136 + ck*8);
        int node = rt*16 + nl;
        *(uint4*)(qkv + ((size_t)y*N_NODES + node)*EFF + z*128 + ck*8) = v;
      }
    }
  }
  grid.sync();

  // ================= Phase C: per-graph attention -> hv (LDS) + h stats =================
  {
    float (*qs)[GSIZE][68] = (float(*)[GSIZE][68])(arena + 8192);
    float (*ks)[GSIZE][68] = (float(*)[GSIZE][68])(arena + 21248);
    float (*vs)[GSIZE][68] = (float(*)[GSIZE][68])(arena + 34304);
    float (*S)[GSIZE][28]  = (float(*)[GSIZE][28])(arena + 47360);
    const unsigned short* qb = qkv;
    const unsigned short* kb = qkv + (size_t)N_NODES*EFF;
    const unsigned short* vb = qkv + (size_t)2*N_NODES*EFF;
    int pipe = t >> 8, t2 = t & 255;
    f32x4 a0 = {0.f,0.f,0.f,0.f}, a1 = {0.f,0.f,0.f,0.f};

    for(int iter = 0; iter < 4; ++iter){
      int head = iter*2 + pipe;
      __syncthreads();
      for(int p = t2; p < 192; p += 256){
        int i = p >> 3, d0 = (p & 7)*8;
        size_t gi = (size_t)(base + i)*EFF + head*DH + d0;
        U16B uq, uk, uv;
        uq.u = *(const uint4*)(qb + gi);
        uk.u = *(const uint4*)(kb + gi);
        uv.u = *(const uint4*)(vb + gi);
        #pragma unroll
        for(int j = 0; j < 8; j++){
          qs[pipe][i][d0+j] = bf2f(uq.s[j]);
          ks[pipe][i][d0+j] = bf2f(uk.s[j]);
          vs[pipe][i][d0+j] = bf2f(uv.s[j]);
        }
      }
      __syncthreads();
      for(int p = t2; p < GSIZE*GSIZE; p += 256){
        int i = p / GSIZE, j = p - i*GSIZE;
        const float4* qi = (const float4*)qs[pipe][i];
        const float4* kj = (const float4*)ks[pipe][j];
        float s = 0.f;
        #pragma unroll
        for(int d = 0; d < 16; ++d){
          float4 a = qi[d], b = kj[d];
          s += a.x*b.x + a.y*b.y + a.z*b.z + a.w*b.w;
        }
        S[pipe][i][j] = s;
      }
      __syncthreads();
      if(t2 < 192){
        int row = t2 >> 3, sl = t2 & 7;
        float v0 = S[pipe][row][sl*3]   * 0.125f;
        float v1 = S[pipe][row][sl*3+1] * 0.125f;
        float v2 = S[pipe][row][sl*3+2] * 0.125f;
        float m0 = fmaxf(fmaxf(v0, v1), v2);
        #pragma unroll
        for(int o = 1; o < 8; o <<= 1) m0 = fmaxf(m0, __shfl_xor(m0, o, 8));
        float e0 = __expf(v0-m0), e1 = __expf(v1-m0), e2 = __expf(v2-m0);
        float su = e0 + e1 + e2;
        #pragma unroll
        for(int o = 1; o < 8; o <<= 1) su += __shfl_xor(su, o, 8);
        float inv = 1.0f / (su + 1e-16f);
        S[pipe][row][sl*3]   = e0*inv;
        S[pipe][row][sl*3+1] = e1*inv;
        S[pipe][row][sl*3+2] = e2*inv;
      }
      __syncthreads();
      {
        int p = t2;
        if(p < 384){
          int i = p >> 4, dq = p & 15;
          #pragma unroll 8
          for(int j = 0; j < GSIZE; ++j){
            float w = S[pipe][i][j];
            float4 v = *(const float4*)&vs[pipe][j][dq*4];
            a0.x += w*v.x; a0.y += w*v.y; a0.z += w*v.z; a0.w += w*v.w;
          }
        }
        p = t2 + 256;
        if(p < 384){
          int i = p >> 4, dq = p & 15;
          #pragma unroll 8
          for(int j = 0; j < GSIZE; ++j){
            float w = S[pipe][i][j];
            float4 v = *(const float4*)&vs[pipe][j][dq*4];
            a1.x += w*v.x; a1.y += w*v.y; a1.z += w*v.z; a1.w += w*v.w;
          }
        }
      }
    }
    __syncthreads();
    if(pipe == 1){
      int p = t2;
      if(p < 384){
        int i = p >> 4, dq = p & 15;
        float4 o; o.x = a0.x*0.125f; o.y = a0.y*0.125f; o.z = a0.z*0.125f; o.w = a0.w*0.125f;
        *(float4*)&hv[i][dq*4] = o;
      }
      p = t2 + 256;
      if(p < 384){
        int i = p >> 4, dq = p & 15;
        float4 o; o.x = a1.x*0.125f; o.y = a1.y*0.125f; o.z = a1.z*0.125f; o.w = a1.w*0.125f;
        *(float4*)&hv[i][dq*4] = o;
      }
    }
    __syncthreads();
    if(pipe == 0){
      #pragma unroll
      for(int slot = 0; slot < 2; ++slot){
        int p = t2 + slot*256;
        if(p < 384){
          int i = p >> 4, dq = p & 15;
          f32x4 a = slot ? a1 : a0;
          float4 hp = *(const float4*)&hv[i][dq*4];
          const float* xr = x + (size_t)(base+i)*DIN + dq*4;
          float4 r1 = *(const float4*)xr;
          float4 r2 = *(const float4*)(xr + 64);
          float4 o;
          o.x = a.x*0.125f + hp.x + r1.x + r2.x;
          o.y = a.y*0.125f + hp.y + r1.y + r2.y;
          o.z = a.z*0.125f + hp.z + r1.z + r2.z;
          o.w = a.w*0.125f + hp.w + r1.w + r2.w;
          *(float4*)&hv[i][dq*4] = o;
        }
      }
    }
    __syncthreads();
    if(t < 64){
      float s1 = 0.f, s2 = 0.f;
      #pragma unroll
      for(int i = 0; i < GSIZE; ++i){ float v = hv[i][t]; s1 += v; s2 += v*v; }
      ws[HP + g*128 + t]      = s1;
      ws[HP + g*128 + 64 + t] = s2;
    }
  }
  grid.sync();

  // ================= Phase D: norm2 + PFF + pgnorm + score + softmax + pool =================
  {
    float* redA   = (float*)(arena + 8192);
    float* stat   = (float*)(arena + 10240);
    float* A2     = (float*)(arena + 10752);
    float* C2     = (float*)(arena + 11008);
    float* a3     = (float*)(arena + 11264);
    float* c3     = (float*)(arena + 11520);
    float* scores = (float*)(arena + 11776);
    float* wsm    = (float*)(arena + 11872);
    float (*hs)[65] = (float(*)[65])(arena + 12288);
    float (*hn)[65] = (float(*)[65])(arena + 18528);
    float (*ts)[65] = (float(*)[65])(arena + 24768);
    const float* wt1  = ws + WT1;
    const float* wt2  = ws + WT2;
    const float* pwt1 = ws + PWT1;
    const float* fb   = ws + FBo;

    {
      int idx = t & 127, grp = t >> 7;
      float s = 0.f;
      for(int p = grp; p < NGRAPH; p += 4) s += ws[HP + p*128 + idx];
      redA[t] = s;
    }
    __syncthreads();
    if(t < 128) stat[t] = redA[t] + redA[t+128] + redA[t+256] + redA[t+384];
    __syncthreads();
    if(t < 64){
      float mean = stat[t] * (1.0f / N_NODES);
      float ex2  = stat[64+t] * (1.0f / N_NODES);
      float cm   = mean * no_ms[t];
      float var  = ex2 - 2.f*cm*mean + cm*cm;
      float rstd = rsqrtf(var + EPSN);
      float a    = no_w[t] * rstd;
      A2[t] = a; C2[t] = no_b[t] - a*cm;
    }
    __syncthreads();
    for(int p = t; p < GSIZE*DH; p += 512){
      int i = p >> 6, d = p & 63;
      float hvv = hv[i][d];
      hs[i][d] = hvv;
      hn[i][d] = A2[d]*hvv + C2[d];
    }
    __syncthreads();
    for(int p = t; p < GSIZE*DH; p += 512){
      int i = p >> 6, c = p & 63;
      float s = fb[c];
      #pragma unroll
      for(int k = 0; k < DH; k++) s += hn[i][k] * wt1[k*DH + c];
      ts[i][c] = gelu_exact(s);
    }
    __syncthreads();
    for(int p = t; p < GSIZE*DH; p += 512){
      int i = p >> 6, c = p & 63;
      float s = fb[64 + c];
      #pragma unroll
      for(int k = 0; k < DH; k++) s += ts[i][k] * wt2[k*DH + c];
      hs[i][c] = hs[i][c] + s;
    }
    __syncthreads();
    if(t < 64){
      float s1 = 0.f, s2 = 0.f;
      for(int i = 0; i < GSIZE; i++){ float v = hs[i][t]; s1 += v; s2 += v*v; }
      float mean = s1 * (1.0f / GSIZE);
      float ex2  = s2 * (1.0f / GSIZE);
      float cm   = mean * pn_ms[t];
      float var  = ex2 - 2.f*cm*mean + cm*cm;
      float rstd = rsqrtf(var + EPSN);
      float a    = pn_w[t] * rstd;
      a3[t] = a; c3[t] = pn_b[t] - a*cm;
    }
    __syncthreads();
    for(int p = t; p < GSIZE*DH; p += 512){
      int i = p >> 6, d = p & 63;
      hn[i][d] = a3[d]*hs[i][d] + c3[d];
    }
    __syncthreads();
    for(int p = t; p < GSIZE*DH; p += 512){
      int i = p >> 6, c = p & 63;
      float s = fb[128 + c];
      #pragma unroll
      for(int k = 0; k < DH; k++) s += hn[i][k] * pwt1[k*DH + c];
      ts[i][c] = gelu_exact(s);
    }
    __syncthreads();
    if(t < GSIZE){
      float s = fb[256];
      for(int c = 0; c < DH; c++) s += ts[t][c] * fb[192 + c];
      scores[t] = s;
    }
    __syncthreads();
    if(t < GSIZE){
      float mx = -1e30f;
      for(int j = 0; j < GSIZE; j++) mx = fmaxf(mx, scores[j]);
      float sum = 0.f;
      for(int j = 0; j < GSIZE; j++) sum += __expf(scores[j] - mx);
      wsm[t] = __expf(scores[t] - mx) / (sum + 1e-16f);
    }
    __syncthreads();
    if(t < DIN){
      float s = 0.f;
      #pragma unroll 8
      for(int i = 0; i < GSIZE; i++) s += wsm[i] * x[(size_t)(base+i)*DIN + t];
      out[(size_t)g*DIN + t] = s;
    }
  }
}

extern "C" void kernel_launch(void* const* d_in, const int* in_sizes, int n_in,
                              void* d_out, int out_size, void* d_ws, size_t ws_size,
                              hipStream_t stream){
  (void)in_sizes; (void)n_in; (void)out_size; (void)ws_size;
  const float* x    = (const float*)d_in[0];
  const float* nq_w = (const float*)d_in[4];
  const float* nq_b = (const float*)d_in[5];
  const float* nq_ms= (const float*)d_in[6];
  const float* wq   = (const float*)d_in[7];
  const float* bq   = (const float*)d_in[8];
  const float* wk   = (const float*)d_in[9];
  const float* bk   = (const float*)d_in[10];
  const float* wv   = (const float*)d_in[11];
  const float* bv   = (const float*)d_in[12];
  const float* no_w = (const float*)d_in[13];
  const float* no_b = (const float*)d_in[14];
  const float* no_ms= (const float*)d_in[15];
  const float* o_w1 = (const float*)d_in[16];
  const float* o_b1 = (const float*)d_in[17];
  const float* o_w2 = (const float*)d_in[18];
  const float* o_b2 = (const float*)d_in[19];
  const float* pn_w = (const float*)d_in[20];
  const float* pn_b = (const float*)d_in[21];
  const float* pn_ms= (const float*)d_in[22];
  const float* p_w1 = (const float*)d_in[23];
  const float* p_b1 = (const float*)d_in[24];
  const float* p_w2 = (const float*)d_in[25];
  const float* p_b2 = (const float*)d_in[26];
  float* ws  = (float*)d_ws;
  float* outp = (float*)d_out;

  void* args[] = {
    (void*)&x,
    (void*)&wq, (void*)&bq, (void*)&wk, (void*)&bk, (void*)&wv, (void*)&bv,
    (void*)&nq_w, (void*)&nq_b, (void*)&nq_ms,
    (void*)&no_w, (void*)&no_b, (void*)&no_ms,
    (void*)&o_w1, (void*)&o_b1, (void*)&o_w2, (void*)&o_b2,
    (void*)&pn_w, (void*)&pn_b, (void*)&pn_ms,
    (void*)&p_w1, (void*)&p_b1, (void*)&p_w2, (void*)&p_b2,
    (void*)&ws, (void*)&outp
  };
  hipLaunchCooperativeKernel((void*)k_mega, dim3(NGRAPH), dim3(512), args, 0, stream);
}

// Round 7
// 205.294 us; speedup vs baseline: 1.7211x; 1.7211x over previous
//
#include <hip/hip_runtime.h>
#include <stdint.h>

// FP32 in/out (established R4). bf16 only for MFMA operands.
// R6 lesson: no cooperative mega-kernel; per-phase grids, no grid.sync.

#define N_NODES 6144
#define GSIZE 24
#define NGRAPH 256
#define DIN 128
#define DH 64
#define EFF 512
#define EPSN 1e-5f

typedef __attribute__((ext_vector_type(8))) __bf16 bf16x8;
typedef __attribute__((ext_vector_type(4))) float f32x4;
union U16B { uint4 u; bf16x8 v; unsigned short s[8]; };

__device__ inline float bf2f(unsigned short u){ return __uint_as_float(((unsigned)u)<<16); }
__device__ inline unsigned short f2bf(float f){
  unsigned u = __float_as_uint(f);
  u += 0x7fff + ((u>>16)&1);
  return (unsigned short)(u>>16);
}
__device__ inline float gelu_exact(float x){ return 0.5f*x*(1.0f+erff(x*0.70710678118654752f)); }

// ---- workspace float offsets ----
#define XP    0         // 48 x 256 floats: x col sum/sumsq partials
#define HP    12288     // 256 x 128 floats: h col stat partials
#define WT1   45056
#define WT2   49152
#define PWT1  53248
#define FBo   57344     // 257 floats
#define WCVT_BYTE  231424   // 3 x 512 x 128 bf16 = 393216 B
#define HCOMB_BYTE 624640   // 6144 x 64 fp32

// ================= K1: k_pre =================
__global__ __launch_bounds__(256)
void k_pre(const float* __restrict__ x,
           const float* __restrict__ o_w1, const float* __restrict__ o_w2,
           const float* __restrict__ p_w1,
           const float* __restrict__ o_b1, const float* __restrict__ o_b2,
           const float* __restrict__ p_b1, const float* __restrict__ p_w2,
           const float* __restrict__ p_b2,
           const float* __restrict__ wq, const float* __restrict__ wk,
           const float* __restrict__ wv,
           float* __restrict__ wsf){
  int t = threadIdx.x;
  int bi = blockIdx.x;
  if(bi < 48){
    int c = t & 127, h = t >> 7;
    const float* xp = x + (size_t)(bi*128 + h*64)*DIN + c;
    float s = 0.f, q = 0.f;
    for(int r = 0; r < 64; ++r){
      float v = xp[(size_t)r*DIN];
      s += v; q += v*v;
    }
    __shared__ float sm[256], sm2[256];
    sm[t] = s; sm2[t] = q;
    __syncthreads();
    if(t < 128){
      wsf[XP + bi*256 + t]       = sm[t] + sm[t+128];
      wsf[XP + bi*256 + 128 + t] = sm2[t] + sm2[t+128];
    }
    return;
  }
  if(bi < 51){
    const float* src; float* dst;
    if(bi == 48){ src = o_w1; dst = wsf + WT1; }
    else if(bi == 49){ src = o_w2; dst = wsf + WT2; }
    else { src = p_w1; dst = wsf + PWT1; }
    for(int p = t; p < DH*DH; p += 256){
      int r = p >> 6, c = p & 63;
      dst[c*DH + r] = src[p];
    }
    if(bi == 48){
      float* fb = wsf + FBo;
      if(t < 64){
        fb[t]       = o_b1[t];
        fb[64 + t]  = o_b2[t];
        fb[128 + t] = p_b1[t];
        fb[192 + t] = p_w2[t];
      }
      if(t == 0) fb[256] = p_b2[0];
    }
    return;
  }
  const float* src = (bi == 51) ? wq : (bi == 52) ? wk : wv;
  unsigned short* dst = (unsigned short*)((char*)wsf + WCVT_BYTE) + (size_t)(bi-51)*EFF*DIN;
  for(int e = t*8; e < EFF*DIN; e += 2048){
    float4 a = *(const float4*)(src + e);
    float4 b = *(const float4*)(src + e + 4);
    U16B o;
    o.s[0]=f2bf(a.x); o.s[1]=f2bf(a.y); o.s[2]=f2bf(a.z); o.s[3]=f2bf(a.w);
    o.s[4]=f2bf(b.x); o.s[5]=f2bf(b.y); o.s[6]=f2bf(b.z); o.s[7]=f2bf(b.w);
    *(uint4*)(dst + e) = o.u;
  }
}

// ================= K2: k_fused =================
// 256 blocks x 512 thr. Per graph: stat-reduce -> x norm frags -> per-head
// QKV MFMA directly into LDS fp32 tiles -> attention (2 pipes x 4 iters).
__global__ __launch_bounds__(512, 1)
void k_fused(const float* __restrict__ x,
             const float* __restrict__ bq, const float* __restrict__ bk,
             const float* __restrict__ bv,
             const float* __restrict__ nq_w, const float* __restrict__ nq_b,
             const float* __restrict__ nq_ms,
             float* __restrict__ ws, float* __restrict__ hcomb){
  __shared__ __align__(16) char arena[52224];
  float (*hv)[68] = (float(*)[68])(arena);                    // 0..6528
  float* A1 = (float*)(arena + 6528);
  float* C1 = (float*)(arena + 7040);
  float (*qs)[GSIZE][68] = (float(*)[GSIZE][68])(arena + 7552);   // 13056
  float (*ks)[GSIZE][68] = (float(*)[GSIZE][68])(arena + 20608);
  float (*vs)[GSIZE][68] = (float(*)[GSIZE][68])(arena + 33664);
  float (*S)[GSIZE][28]  = (float(*)[GSIZE][28])(arena + 46720);  // 5376
  float* redA = (float*)(arena + 7552);   // alias qs (preamble only)
  float* redB = (float*)(arena + 11648);

  int t = threadIdx.x, g = blockIdx.x, base = g * GSIZE;
  const unsigned short* wcvt = (const unsigned short*)((const char*)ws + WCVT_BYTE);

  // ---- reduce x col-stat partials -> A1/C1 ----
  {
    int c = t & 127, grp = t >> 7;   // grp 0..3
    float s = 0.f, q = 0.f;
    for(int p = grp*12; p < grp*12 + 12; ++p){
      s += ws[XP + p*256 + c];
      q += ws[XP + p*256 + 128 + c];
    }
    redA[t] = s; redB[t] = q;
  }
  __syncthreads();
  if(t < 128){
    float s = redA[t] + redA[t+128] + redA[t+256] + redA[t+384];
    float q = redB[t] + redB[t+128] + redB[t+256] + redB[t+384];
    float mean = s * (1.0f / N_NODES);
    float ex2  = q * (1.0f / N_NODES);
    float cm   = mean * nq_ms[t];
    float var  = ex2 - 2.f*cm*mean + cm*cm;
    float rstd = rsqrtf(var + EPSN);
    float a    = nq_w[t] * rstd;
    A1[t] = a; C1[t] = nq_b[t] - a*cm;
  }
  __syncthreads();

  int pipe = t >> 8, t2 = t & 255;
  int wv4 = (t >> 6) & 3, lane = t & 63, m = lane & 15, quad = lane >> 4;
  int mt = wv4 & 1, cth = wv4 >> 1;
  int node = mt*16 + m;
  int xrow = base + node; if(xrow > N_NODES-1) xrow = N_NODES-1;

  // normalized x fragments (B operand), per wave's m-tile, reused all iters
  bf16x8 xfr[4];
  #pragma unroll
  for(int kk = 0; kk < 4; kk++){
    int k0 = kk*32 + quad*8;
    float4 a = *(const float4*)(x + (size_t)xrow*DIN + k0);
    float4 b = *(const float4*)(x + (size_t)xrow*DIN + k0 + 4);
    U16B u;
    u.s[0] = f2bf(a.x*A1[k0+0] + C1[k0+0]);
    u.s[1] = f2bf(a.y*A1[k0+1] + C1[k0+1]);
    u.s[2] = f2bf(a.z*A1[k0+2] + C1[k0+2]);
    u.s[3] = f2bf(a.w*A1[k0+3] + C1[k0+3]);
    u.s[4] = f2bf(b.x*A1[k0+4] + C1[k0+4]);
    u.s[5] = f2bf(b.y*A1[k0+5] + C1[k0+5]);
    u.s[6] = f2bf(b.z*A1[k0+6] + C1[k0+6]);
    u.s[7] = f2bf(b.w*A1[k0+7] + C1[k0+7]);
    xfr[kk] = u.v;
  }

  f32x4 a0 = {0.f,0.f,0.f,0.f}, a1 = {0.f,0.f,0.f,0.f};

  for(int iter = 0; iter < 4; ++iter){
    int head = iter*2 + pipe;
    __syncthreads();                          // prior PV done; tiles reusable
    // ---- QKV MFMA for this pipe's head: 6 tile-tasks per wave ----
    #pragma unroll
    for(int task = 0; task < 6; ++task){
      int tk = cth*6 + task;                  // 0..11
      int mat = tk >> 2, ctm = tk & 3;
      const unsigned short* wp = wcvt + (size_t)mat*EFF*DIN;
      int wrow = head*64 + ctm*16 + m;
      f32x4 acc = {0.f,0.f,0.f,0.f};
      #pragma unroll
      for(int kk = 0; kk < 4; kk++){
        U16B b8; b8.u = *(const uint4*)(wp + (size_t)wrow*DIN + kk*32 + quad*8);
        acc = __builtin_amdgcn_mfma_f32_16x16x32_bf16(b8.v, xfr[kk], acc, 0, 0, 0);
      }
      const float* bias = (mat==0) ? bq : (mat==1) ? bk : bv;
      float4 bv4 = *(const float4*)(bias + head*64 + ctm*16 + quad*4);
      float (*tile)[68] = (mat==0) ? qs[pipe] : (mat==1) ? ks[pipe] : vs[pipe];
      if(mt == 0 || m < 8){                   // node < 24 only
        int d0 = ctm*16 + quad*4;
        tile[node][d0+0] = acc[0] + bv4.x;
        tile[node][d0+1] = acc[1] + bv4.y;
        tile[node][d0+2] = acc[2] + bv4.z;
        tile[node][d0+3] = acc[3] + bv4.w;
      }
    }
    __syncthreads();                          // tiles ready
    // ---- S + softmax fused (8 lanes/row, 3 cols each, shuffle-local) ----
    if(t2 < 192){
      int row = t2 >> 3, sl = t2 & 7;
      const float4* qi = (const float4*)qs[pipe][row];
      const float4* k0p = (const float4*)ks[pipe][sl*3];
      const float4* k1p = (const float4*)ks[pipe][sl*3+1];
      const float4* k2p = (const float4*)ks[pipe][sl*3+2];
      float s0 = 0.f, s1 = 0.f, s2 = 0.f;
      #pragma unroll
      for(int d = 0; d < 16; ++d){
        float4 qv = qi[d];
        float4 ka = k0p[d], kb = k1p[d], kc = k2p[d];
        s0 += qv.x*ka.x + qv.y*ka.y + qv.z*ka.z + qv.w*ka.w;
        s1 += qv.x*kb.x + qv.y*kb.y + qv.z*kb.z + qv.w*kb.w;
        s2 += qv.x*kc.x + qv.y*kc.y + qv.z*kc.z + qv.w*kc.w;
      }
      s0 *= 0.125f; s1 *= 0.125f; s2 *= 0.125f;
      float m0 = fmaxf(fmaxf(s0, s1), s2);
      #pragma unroll
      for(int o = 1; o < 8; o <<= 1) m0 = fmaxf(m0, __shfl_xor(m0, o, 8));
      float e0 = __expf(s0-m0), e1 = __expf(s1-m0), e2 = __expf(s2-m0);
      float su = e0 + e1 + e2;
      #pragma unroll
      for(int o = 1; o < 8; o <<= 1) su += __shfl_xor(su, o, 8);
      float inv = 1.0f / (su + 1e-16f);
      S[pipe][row][sl*3]   = e0*inv;
      S[pipe][row][sl*3+1] = e1*inv;
      S[pipe][row][sl*3+2] = e2*inv;
    }
    __syncthreads();
    // ---- PV accumulate ----
    {
      int p = t2;
      if(p < 384){
        int i = p >> 4, dq = p & 15;
        #pragma unroll 8
        for(int j = 0; j < GSIZE; ++j){
          float w = S[pipe][i][j];
          float4 v = *(const float4*)&vs[pipe][j][dq*4];
          a0.x += w*v.x; a0.y += w*v.y; a0.z += w*v.z; a0.w += w*v.w;
        }
      }
      p = t2 + 256;
      if(p < 384){
        int i = p >> 4, dq = p & 15;
        #pragma unroll 8
        for(int j = 0; j < GSIZE; ++j){
          float w = S[pipe][i][j];
          float4 v = *(const float4*)&vs[pipe][j][dq*4];
          a1.x += w*v.x; a1.y += w*v.y; a1.z += w*v.z; a1.w += w*v.w;
        }
      }
    }
  }
  __syncthreads();
  if(pipe == 1){
    int p = t2;
    if(p < 384){
      int i = p >> 4, dq = p & 15;
      float4 o; o.x = a0.x*0.125f; o.y = a0.y*0.125f; o.z = a0.z*0.125f; o.w = a0.w*0.125f;
      *(float4*)&hv[i][dq*4] = o;
    }
    p = t2 + 256;
    if(p < 384){
      int i = p >> 4, dq = p & 15;
      float4 o; o.x = a1.x*0.125f; o.y = a1.y*0.125f; o.z = a1.z*0.125f; o.w = a1.w*0.125f;
      *(float4*)&hv[i][dq*4] = o;
    }
  }
  __syncthreads();
  if(pipe == 0){
    #pragma unroll
    for(int slot = 0; slot < 2; ++slot){
      int p = t2 + slot*256;
      if(p < 384){
        int i = p >> 4, dq = p & 15;
        f32x4 a = slot ? a1 : a0;
        float4 hp = *(const float4*)&hv[i][dq*4];
        const float* xr = x + (size_t)(base+i)*DIN + dq*4;
        float4 r1 = *(const float4*)xr;
        float4 r2 = *(const float4*)(xr + 64);
        float4 o;
        o.x = a.x*0.125f + hp.x + r1.x + r2.x;
        o.y = a.y*0.125f + hp.y + r1.y + r2.y;
        o.z = a.z*0.125f + hp.z + r1.z + r2.z;
        o.w = a.w*0.125f + hp.w + r1.w + r2.w;
        *(float4*)&hv[i][dq*4] = o;
        *(float4*)(hcomb + (size_t)(base+i)*DH + dq*4) = o;
      }
    }
  }
  __syncthreads();
  if(t < 64){
    float s1 = 0.f, s2 = 0.f;
    #pragma unroll
    for(int i = 0; i < GSIZE; ++i){ float v = hv[i][t]; s1 += v; s2 += v*v; }
    ws[HP + g*128 + t]      = s1;
    ws[HP + g*128 + 64 + t] = s2;
  }
}

// ================= K3: k_final =================
__global__ __launch_bounds__(256)
void k_final(const float* __restrict__ x,
             const float* __restrict__ hbuf, const float* __restrict__ ws,
             const float* __restrict__ no_w, const float* __restrict__ no_b,
             const float* __restrict__ no_ms,
             const float* __restrict__ pn_w, const float* __restrict__ pn_b,
             const float* __restrict__ pn_ms,
             float* __restrict__ out){
  const float* wt1  = ws + WT1;
  const float* wt2  = ws + WT2;
  const float* pwt1 = ws + PWT1;
  const float* fb   = ws + FBo;

  __shared__ float hs[GSIZE][DH+1];
  __shared__ float hn[GSIZE][DH+1];
  __shared__ float ts[GSIZE][DH+1];
  __shared__ float A2[DH], C2[DH];
  __shared__ float a3[DH], c3[DH];
  __shared__ float scores[GSIZE], wsm[GSIZE];
  __shared__ float redA[256], redB[256];

  int t = threadIdx.x;
  int base = blockIdx.x * GSIZE;

  {
    int c = t & 63, grp = t >> 6;
    float s1 = 0.f, s2 = 0.f;
    for(int p = grp; p < NGRAPH; p += 4){
      s1 += ws[HP + p*128 + c];
      s2 += ws[HP + p*128 + 64 + c];
    }
    redA[t] = s1; redB[t] = s2;
  }
  __syncthreads();
  if(t < DH){
    float s1 = redA[t] + redA[t+64] + redA[t+128] + redA[t+192];
    float s2 = redB[t] + redB[t+64] + redB[t+128] + redB[t+192];
    float mean = s1 * (1.0f / N_NODES);
    float ex2  = s2 * (1.0f / N_NODES);
    float cm   = mean * no_ms[t];
    float var  = ex2 - 2.f*cm*mean + cm*cm;
    float rstd = rsqrtf(var + EPSN);
    float a    = no_w[t] * rstd;
    A2[t] = a; C2[t] = no_b[t] - a*cm;
  }
  __syncthreads();
  for(int p = t; p < GSIZE*DH; p += 256){
    int i = p >> 6, d = p & 63;
    float hvv = hbuf[(size_t)(base+i)*DH + d];
    hs[i][d] = hvv;
    hn[i][d] = A2[d]*hvv + C2[d];
  }
  __syncthreads();
  for(int p = t; p < GSIZE*DH; p += 256){
    int i = p >> 6, c = p & 63;
    float s = fb[c];
    #pragma unroll
    for(int k = 0; k < DH; k++) s += hn[i][k] * wt1[k*DH + c];
    ts[i][c] = gelu_exact(s);
  }
  __syncthreads();
  for(int p = t; p < GSIZE*DH; p += 256){
    int i = p >> 6, c = p & 63;
    float s = fb[64 + c];
    #pragma unroll
    for(int k = 0; k < DH; k++) s += ts[i][k] * wt2[k*DH + c];
    hs[i][c] = hs[i][c] + s;
  }
  __syncthreads();
  if(t < DH){
    float s1 = 0.f, s2 = 0.f;
    for(int i = 0; i < GSIZE; i++){ float v = hs[i][t]; s1 += v; s2 += v*v; }
    float mean = s1 * (1.0f / GSIZE);
    float ex2  = s2 * (1.0f / GSIZE);
    float cm   = mean * pn_ms[t];
    float var  = ex2 - 2.f*cm*mean + cm*cm;
    float rstd = rsqrtf(var + EPSN);
    float a    = pn_w[t] * rstd;
    a3[t] = a; c3[t] = pn_b[t] - a*cm;
  }
  __syncthreads();
  for(int p = t; p < GSIZE*DH; p += 256){
    int i = p >> 6, d = p & 63;
    hn[i][d] = a3[d]*hs[i][d] + c3[d];
  }
  __syncthreads();
  for(int p = t; p < GSIZE*DH; p += 256){
    int i = p >> 6, c = p & 63;
    float s = fb[128 + c];
    #pragma unroll
    for(int k = 0; k < DH; k++) s += hn[i][k] * pwt1[k*DH + c];
    ts[i][c] = gelu_exact(s);
  }
  __syncthreads();
  if(t < GSIZE){
    float s = fb[256];
    for(int c = 0; c < DH; c++) s += ts[t][c] * fb[192 + c];
    scores[t] = s;
  }
  __syncthreads();
  if(t < GSIZE){
    float mx = -1e30f;
    for(int j = 0; j < GSIZE; j++) mx = fmaxf(mx, scores[j]);
    float sum = 0.f;
    for(int j = 0; j < GSIZE; j++) sum += __expf(scores[j] - mx);
    wsm[t] = __expf(scores[t] - mx) / (sum + 1e-16f);
  }
  __syncthreads();
  if(t < DIN){
    float s = 0.f;
    #pragma unroll 8
    for(int i = 0; i < GSIZE; i++) s += wsm[i] * x[(size_t)(base+i)*DIN + t];
    out[(size_t)blockIdx.x*DIN + t] = s;
  }
}

extern "C" void kernel_launch(void* const* d_in, const int* in_sizes, int n_in,
                              void* d_out, int out_size, void* d_ws, size_t ws_size,
                              hipStream_t stream){
  (void)in_sizes; (void)n_in; (void)out_size; (void)ws_size;
  const float* x    = (const float*)d_in[0];
  const float* nq_w = (const float*)d_in[4];
  const float* nq_b = (const float*)d_in[5];
  const float* nq_ms= (const float*)d_in[6];
  const float* wq   = (const float*)d_in[7];
  const float* bq   = (const float*)d_in[8];
  const float* wk   = (const float*)d_in[9];
  const float* bk   = (const float*)d_in[10];
  const float* wv   = (const float*)d_in[11];
  const float* bv   = (const float*)d_in[12];
  const float* no_w = (const float*)d_in[13];
  const float* no_b = (const float*)d_in[14];
  const float* no_ms= (const float*)d_in[15];
  const float* o_w1 = (const float*)d_in[16];
  const float* o_b1 = (const float*)d_in[17];
  const float* o_w2 = (const float*)d_in[18];
  const float* o_b2 = (const float*)d_in[19];
  const float* pn_w = (const float*)d_in[20];
  const float* pn_b = (const float*)d_in[21];
  const float* pn_ms= (const float*)d_in[22];
  const float* p_w1 = (const float*)d_in[23];
  const float* p_b1 = (const float*)d_in[24];
  const float* p_w2 = (const float*)d_in[25];
  const float* p_b2 = (const float*)d_in[26];

  float* ws = (float*)d_ws;
  float* hcomb = (float*)((char*)d_ws + HCOMB_BYTE);

  k_pre<<<54, 256, 0, stream>>>(x, o_w1, o_w2, p_w1, o_b1, o_b2, p_b1, p_w2, p_b2,
                                wq, wk, wv, ws);
  k_fused<<<NGRAPH, 512, 0, stream>>>(x, bq, bk, bv, nq_w, nq_b, nq_ms, ws, hcomb);
  k_final<<<NGRAPH, 256, 0, stream>>>(x, hcomb, ws, no_w, no_b, no_ms,
                                      pn_w, pn_b, pn_ms, (float*)d_out);
}